// Round 5
// baseline (198.003 us; speedup 1.0000x reference)
//
#include <hip/hip_runtime.h>

namespace {

constexpr int T = 5, F = 30, H = 20;
constexpr int BATCH = 131072;
constexpr int BPB = 64;   // batch rows per block (one per lane)
constexpr int XP = 31;    // padded x row stride (odd dwords -> conflict-free b32)
constexpr int HP = 21;    // padded h row stride

typedef float f32x2 __attribute__((ext_vector_type(2)));

__device__ __forceinline__ f32x2 fma2(f32x2 a, f32x2 b, f32x2 c) {
  return __builtin_elementwise_fma(a, b, c);   // v_pk_fma_f32
}

// sigmoid via raw exp2/rcp: v=+inf -> 1, v=-inf -> 0, no NaN paths.
__device__ __forceinline__ float sig(float v) {
  return __builtin_amdgcn_rcpf(1.0f + __builtin_amdgcn_exp2f(v * -1.44269504f));
}
// tanh(v) = 2*sigmoid(2v) - 1; saturates correctly at +-inf.
__device__ __forceinline__ float tanh_s(float v) {
  return fmaf(2.0f,
              __builtin_amdgcn_rcpf(1.0f + __builtin_amdgcn_exp2f(v * -2.88539008f)),
              -1.0f);
}

__global__ __launch_bounds__(256, 5) void lstm_stage(
    const float* __restrict__ x,
    const float* __restrict__ wf, const float* __restrict__ wi,
    const float* __restrict__ wo, const float* __restrict__ wc,
    const float* __restrict__ uf, const float* __restrict__ ui,
    const float* __restrict__ uo, const float* __restrict__ uc,
    const float* __restrict__ bf, const float* __restrict__ bi,
    const float* __restrict__ bo, const float* __restrict__ bc,
    float* __restrict__ out)
{
  const int tid  = threadIdx.x;
  const int lane = tid & 63;
  const int wv   = tid >> 6;                              // 0..3
  const int jo   = __builtin_amdgcn_readfirstlane(wv * 5);
  const int odd  = __builtin_amdgcn_readfirstlane(wv & 1);
  const int pb   = jo + odd;            // even pair base -> 8B-aligned s_load pairs
  const int sj   = odd ? jo : jo + 4;   // unpaired column
  const int b0   = blockIdx.x * BPB;

  const float* xbase = x + (size_t)b0 * (T * F);   // block's x slab
  float*       obase = out + (size_t)b0 * (T * H); // block's out slab

  __shared__ float xs[2][BPB][XP];
  __shared__ float hbuf[2][BPB][HP];

  // Hoisted biases (uniform -> SGPRs)
  const f32x2 bF0 = *(const f32x2*)(bf + pb), bF1 = *(const f32x2*)(bf + pb + 2);
  const f32x2 bI0 = *(const f32x2*)(bi + pb), bI1 = *(const f32x2*)(bi + pb + 2);
  const f32x2 bO0 = *(const f32x2*)(bo + pb), bO1 = *(const f32x2*)(bo + pb + 2);
  const f32x2 bC0 = *(const f32x2*)(bc + pb), bC1 = *(const f32x2*)(bc + pb + 2);
  const float bFs = bf[sj], bIs = bi[sj], bOs = bo[sj], bCs = bc[sj];

  f32x2 c0 = {0.f, 0.f}, c1 = {0.f, 0.f};
  float cs = 0.f;

  // ---- prologue: stage x[., t=0, .] (coalesced: consecutive tids hit
  // consecutive columns; ~5 lines/instr instead of 64) ----
  float pf[8];
#pragma unroll
  for (int k = 0; k < 7; ++k) {
    unsigned f = tid + k * 256;
    pf[k] = xbase[(f / 30u) * (T * F) + (f % 30u)];
  }
  if (tid < 128) {
    unsigned f = tid + 7 * 256;
    pf[7] = xbase[(f / 30u) * (T * F) + (f % 30u)];
  }
#pragma unroll
  for (int k = 0; k < 7; ++k) {
    unsigned f = tid + k * 256;
    xs[0][f / 30u][f % 30u] = pf[k];
  }
  if (tid < 128) {
    unsigned f = tid + 7 * 256;
    xs[0][f / 30u][f % 30u] = pf[7];
  }
  __syncthreads();

  int cur = 0;
  for (int t = 0; t < T; ++t) {
    // 1. issue next-t prefetch NOW; vmcnt-wait lands after the FMA phase (T14)
    if (t + 1 < T) {
#pragma unroll
      for (int k = 0; k < 7; ++k) {
        unsigned f = tid + k * 256;
        pf[k] = xbase[(f / 30u) * (T * F) + (t + 1) * F + (f % 30u)];
      }
      if (tid < 128) {
        unsigned f = tid + 7 * 256;
        pf[7] = xbase[(f / 30u) * (T * F) + (t + 1) * F + (f % 30u)];
      }
    }

    // 2. gate accumulators
    f32x2 f0 = bF0, f1 = bF1;  float fs = bFs;
    f32x2 i0 = bI0, i1 = bI1;  float is = bIs;
    f32x2 o0 = bO0, o1 = bO1;  float os = bOs;
    f32x2 g0 = bC0, g1 = bC1;  float gs = bCs;

    // input projection: x from LDS (stride-31 rows: conflict-free b32)
    const float* xr = xs[cur][lane];
#pragma unroll
    for (int k = 0; k < F; ++k) {
      const float xk = xr[k];
      const f32x2 x2 = {xk, xk};
      const int r = k * H;
      f0 = fma2(x2, *(const f32x2*)(wf + r + pb),     f0);
      f1 = fma2(x2, *(const f32x2*)(wf + r + pb + 2), f1);
      fs = fmaf(xk, wf[r + sj], fs);
      i0 = fma2(x2, *(const f32x2*)(wi + r + pb),     i0);
      i1 = fma2(x2, *(const f32x2*)(wi + r + pb + 2), i1);
      is = fmaf(xk, wi[r + sj], is);
      o0 = fma2(x2, *(const f32x2*)(wo + r + pb),     o0);
      o1 = fma2(x2, *(const f32x2*)(wo + r + pb + 2), o1);
      os = fmaf(xk, wo[r + sj], os);
      g0 = fma2(x2, *(const f32x2*)(wc + r + pb),     g0);
      g1 = fma2(x2, *(const f32x2*)(wc + r + pb + 2), g1);
      gs = fmaf(xk, wc[r + sj], gs);
    }

    // recurrent projection from hbuf[cur] (t=0: h==0, skip — matches ref)
    if (t > 0) {
      const float* hrow = hbuf[cur][lane];
#pragma unroll
      for (int k = 0; k < H; ++k) {
        const float hv = hrow[k];
        const f32x2 h2 = {hv, hv};
        const int r = k * H;
        f0 = fma2(h2, *(const f32x2*)(uf + r + pb),     f0);
        f1 = fma2(h2, *(const f32x2*)(uf + r + pb + 2), f1);
        fs = fmaf(hv, uf[r + sj], fs);
        i0 = fma2(h2, *(const f32x2*)(ui + r + pb),     i0);
        i1 = fma2(h2, *(const f32x2*)(ui + r + pb + 2), i1);
        is = fmaf(hv, ui[r + sj], is);
        o0 = fma2(h2, *(const f32x2*)(uo + r + pb),     o0);
        o1 = fma2(h2, *(const f32x2*)(uo + r + pb + 2), o1);
        os = fmaf(hv, uo[r + sj], os);
        g0 = fma2(h2, *(const f32x2*)(uc + r + pb),     g0);
        g1 = fma2(h2, *(const f32x2*)(uc + r + pb + 2), g1);
        gs = fmaf(hv, uc[r + sj], gs);
      }
    }

    // 3. gates + state update; publish h -> hbuf[cur^1]
    float* hw = hbuf[cur ^ 1][lane];
    {
      float fg, ig, og, ch, cn;
#pragma unroll
      for (int e = 0; e < 2; ++e) {
        fg = sig(f0[e]); ig = sig(i0[e]); og = sig(o0[e]); ch = tanh_s(g0[e]);
        cn = fmaf(fg, c0[e], ig * ch);
        c0[e] = cn;
        hw[pb + e] = og * tanh_s(cn);
      }
#pragma unroll
      for (int e = 0; e < 2; ++e) {
        fg = sig(f1[e]); ig = sig(i1[e]); og = sig(o1[e]); ch = tanh_s(g1[e]);
        cn = fmaf(fg, c1[e], ig * ch);
        c1[e] = cn;
        hw[pb + 2 + e] = og * tanh_s(cn);
      }
      fg = sig(fs); ig = sig(is); og = sig(os); ch = tanh_s(gs);
      cn = fmaf(fg, cs, ig * ch);
      cs = cn;
      hw[sj] = og * tanh_s(cn);
    }

    // write prefetched x into xs[cur^1] (vmcnt wait was covered by FMA phase)
    if (t + 1 < T) {
#pragma unroll
      for (int k = 0; k < 7; ++k) {
        unsigned f = tid + k * 256;
        xs[cur ^ 1][f / 30u][f % 30u] = pf[k];
      }
      if (tid < 128) {
        unsigned f = tid + 7 * 256;
        xs[cur ^ 1][f / 30u][f % 30u] = pf[7];
      }
    }

    __syncthreads();   // publish xs[cur^1], hbuf[cur^1] to all waves

    // 4. coalesced out-store of h_t from hbuf[cur^1]: 1280 floats, flat order
#pragma unroll
    for (int k = 0; k < 5; ++k) {
      unsigned flat = tid + k * 256;
      unsigned r = flat / 20u, j = flat % 20u;
      obase[r * (T * H) + t * H + j] = hbuf[cur ^ 1][r][j];
    }

    cur ^= 1;
  }
}

} // namespace

extern "C" void kernel_launch(void* const* d_in, const int* in_sizes, int n_in,
                              void* d_out, int out_size, void* d_ws, size_t ws_size,
                              hipStream_t stream) {
  const float* x  = (const float*)d_in[0];
  const float* wf = (const float*)d_in[1];
  const float* wi = (const float*)d_in[2];
  const float* wo = (const float*)d_in[3];
  const float* wc = (const float*)d_in[4];
  const float* uf = (const float*)d_in[5];
  const float* ui = (const float*)d_in[6];
  const float* uo = (const float*)d_in[7];
  const float* uc = (const float*)d_in[8];
  const float* bf = (const float*)d_in[9];
  const float* bi = (const float*)d_in[10];
  const float* bo = (const float*)d_in[11];
  const float* bc = (const float*)d_in[12];
  float* out = (float*)d_out;

  dim3 block(256);
  dim3 grid(BATCH / BPB);   // 2048 blocks
  hipLaunchKernelGGL(lstm_stage, grid, block, 0, stream,
                     x, wf, wi, wo, wc, uf, ui, uo, uc, bf, bi, bo, bc, out);
}

// Round 6
// 60.577 us; speedup vs baseline: 3.2686x; 3.2686x over previous
//
#include <hip/hip_runtime.h>
#include <hip/hip_bf16.h>

namespace {

constexpr int T = 5, F = 30, H = 20;
constexpr int BATCH = 131072;
constexpr int BPB = 64;    // batch rows per block
constexpr int XS = 36;     // x LDS row stride (dwords): 144B rows -> 16B-aligned b128, 2-way banks
constexpr int HS = 36;     // h LDS row stride

typedef __attribute__((ext_vector_type(8))) short bf16x8;
typedef __attribute__((ext_vector_type(4))) float f32x4;

union FragU { __hip_bfloat162 h2[4]; bf16x8 v; };

__device__ __forceinline__ float sig(float v) {
  return __builtin_amdgcn_rcpf(1.0f + __builtin_amdgcn_exp2f(v * -1.44269504f));
}
// tanh(v) = 2*sigmoid(2v) - 1; saturates correctly at +-inf, no NaN paths.
__device__ __forceinline__ float tanh_s(float v) {
  return fmaf(2.0f,
              __builtin_amdgcn_rcpf(1.0f + __builtin_amdgcn_exp2f(v * -2.88539008f)),
              -1.0f);
}

__global__ __launch_bounds__(256, 3) void lstm_mfma(
    const float* __restrict__ x,
    const float* __restrict__ wf, const float* __restrict__ wi,
    const float* __restrict__ wo, const float* __restrict__ wc,
    const float* __restrict__ uf, const float* __restrict__ ui,
    const float* __restrict__ uo, const float* __restrict__ uc,
    const float* __restrict__ bf, const float* __restrict__ bi,
    const float* __restrict__ bo, const float* __restrict__ bc,
    float* __restrict__ out)
{
  const int tid  = threadIdx.x;
  const int lane = tid & 63;
  const int wv   = tid >> 6;          // wave id 0..3 = N-tile (16 batch rows)
  const int r15  = lane & 15;
  const int q    = lane >> 4;         // 16-lane group -> k-slice 8q..8q+7
  const int b0   = blockIdx.x * BPB;

  const float* xbase = x + (size_t)b0 * (T * F);
  float*       obase = out + (size_t)b0 * (T * H);

  __shared__ __align__(16) float xs[2][BPB][XS];     // 18.4 KB (double-buffered x tile)
  __shared__ __align__(16) float hb[BPB][HS];        //  9.2 KB (current h, K-padded)
  __shared__ __align__(16) float hist[BPB][T * H];   // 25.6 KB (all h_t, drained at end)

  // ---- one-time: A-side weight fragments (W', U' with rows hidx = 4*jj + g) ----
  // A layout: lane holds row (16m + r15), k = 8q + i. g/jj derived from that row.
  const int gA  = r15 & 3;
  const int jA  = r15 >> 2;
  const float* Wg = (gA == 0) ? wf : (gA == 1) ? wi : (gA == 2) ? wo : wc;
  const float* Ug = (gA == 0) ? uf : (gA == 1) ? ui : (gA == 2) ? uo : uc;

  bf16x8 wfrag[5], ufrag[5];
#pragma unroll
  for (int m = 0; m < 5; ++m) {
    const int jj = 4 * m + jA;
    FragU fw, fu;
#pragma unroll
    for (int e = 0; e < 4; ++e) {
      const int k0 = 8 * q + 2 * e, k1 = k0 + 1;
      float w0 = (k0 < F) ? Wg[k0 * H + jj] : 0.f;
      float w1 = (k1 < F) ? Wg[k1 * H + jj] : 0.f;
      fw.h2[e] = __float22bfloat162_rn(float2{w0, w1});
      float u0 = (k0 < H) ? Ug[k0 * H + jj] : 0.f;
      float u1 = (k1 < H) ? Ug[k1 * H + jj] : 0.f;
      fu.h2[e] = __float22bfloat162_rn(float2{u0, u1});
    }
    wfrag[m] = fw.v;
    ufrag[m] = fu.v;
  }

  // D-side: lane's acc[m] regs = gates f,i,o,c of hidden jj = 4m + q, batch row 16wv+r15.
  f32x4 bfr[5];
#pragma unroll
  for (int m = 0; m < 5; ++m) {
    const int jj = 4 * m + q;
    bfr[m] = f32x4{bf[jj], bi[jj], bo[jj], bc[jj]};
  }

  // ---- zero K-pad columns (persist across t; data cols rewritten each t) ----
  for (int i = tid; i < BPB * 6 * 2; i += 256) {      // xs cols 30..35, both buffers
    int bsel = i / (BPB * 6); int rr = (i / 6) % BPB; int cc = i % 6;
    xs[bsel][rr][30 + cc] = 0.f;
  }
  for (int i = tid; i < BPB * 16; i += 256) {         // hb cols 20..35
    hb[i / 16][20 + (i % 16)] = 0.f;
  }
  // stage x(t=0), coalesced
  for (int i = tid; i < BPB * F; i += 256) {
    xs[0][i / F][i % F] = xbase[(i / F) * (T * F) + (i % F)];
  }
  __syncthreads();

  const int row = 16 * wv + r15;      // this lane's batch row (= its D column)
  float cst[5];
#pragma unroll
  for (int m = 0; m < 5; ++m) cst[m] = 0.f;

  float pf[8];
  int cur = 0;
  for (int t = 0; t < T; ++t) {
    // T14: issue next-t x loads now; ds_write happens after barrier, latency
    // hides under MFMA + gate math.
    if (t + 1 < T) {
#pragma unroll
      for (int k2 = 0; k2 < 8; ++k2) {
        int f = tid + k2 * 256;
        pf[k2] = (f < BPB * F)
                   ? xbase[(f / F) * (T * F) + (t + 1) * F + (f % F)] : 0.f;
      }
    }

    // B-frag of x^T: lane's own row, k = 8q..8q+7 (cols 30,31 are zero pad)
    FragU fx;
    {
      const float* xp = &xs[cur][row][8 * q];
      float4 lo = *(const float4*)(xp);
      float4 hi = *(const float4*)(xp + 4);
      fx.h2[0] = __float22bfloat162_rn(float2{lo.x, lo.y});
      fx.h2[1] = __float22bfloat162_rn(float2{lo.z, lo.w});
      fx.h2[2] = __float22bfloat162_rn(float2{hi.x, hi.y});
      fx.h2[3] = __float22bfloat162_rn(float2{hi.z, hi.w});
    }

    f32x4 acc[5];
#pragma unroll
    for (int m = 0; m < 5; ++m)
      acc[m] = __builtin_amdgcn_mfma_f32_16x16x32_bf16(wfrag[m], fx.v, bfr[m], 0, 0, 0);

    if (t > 0) {   // recurrent term; t=0 has h=0 (matches reference exactly)
      FragU fh;
      const float* hp = &hb[row][8 * q];
      float4 lo = *(const float4*)(hp);
      float4 hi = *(const float4*)(hp + 4);
      fh.h2[0] = __float22bfloat162_rn(float2{lo.x, lo.y});
      fh.h2[1] = __float22bfloat162_rn(float2{lo.z, lo.w});
      fh.h2[2] = __float22bfloat162_rn(float2{hi.x, hi.y});
      fh.h2[3] = __float22bfloat162_rn(float2{hi.z, hi.w});
#pragma unroll
      for (int m = 0; m < 5; ++m)
        acc[m] = __builtin_amdgcn_mfma_f32_16x16x32_bf16(ufrag[m], fh.v, acc[m], 0, 0, 0);
    }

    // gate math: fully lane-local (regs 0..3 = f,i,o,c of hidden jj=4m+q)
    float hnew[5];
#pragma unroll
    for (int m = 0; m < 5; ++m) {
      float fg = sig(acc[m][0]);
      float ig = sig(acc[m][1]);
      float og = sig(acc[m][2]);
      float ch = tanh_s(acc[m][3]);
      float cn = fmaf(fg, cst[m], ig * ch);
      cst[m] = cn;
      hnew[m] = og * tanh_s(cn);
    }

    __syncthreads();   // everyone done READING hb and xs[cur]

    // publish h_t (for next-t B-frag) + append to hist
#pragma unroll
    for (int m = 0; m < 5; ++m) {
      const int jj = 4 * m + q;
      hb[row][jj] = hnew[m];
      hist[row][t * H + jj] = hnew[m];
    }
    // write prefetched x(t+1) into the other buffer
    if (t + 1 < T) {
#pragma unroll
      for (int k2 = 0; k2 < 8; ++k2) {
        int f = tid + k2 * 256;
        if (f < BPB * F) xs[cur ^ 1][f / F][f % F] = pf[k2];
      }
    }
    __syncthreads();   // writes visible before next t
    cur ^= 1;
  }

  // ---- coalesced full-line drain: block's contiguous 25.6 KB out slab ----
  const float4* hsrc = (const float4*)&hist[0][0];
#pragma unroll
  for (int k2 = 0; k2 < 7; ++k2) {
    int f4 = tid + k2 * 256;
    if (f4 < BPB * T * H / 4) {
      *(float4*)(obase + 4 * f4) = hsrc[f4];
    }
  }
}

} // namespace

extern "C" void kernel_launch(void* const* d_in, const int* in_sizes, int n_in,
                              void* d_out, int out_size, void* d_ws, size_t ws_size,
                              hipStream_t stream) {
  const float* x  = (const float*)d_in[0];
  const float* wf = (const float*)d_in[1];
  const float* wi = (const float*)d_in[2];
  const float* wo = (const float*)d_in[3];
  const float* wc = (const float*)d_in[4];
  const float* uf = (const float*)d_in[5];
  const float* ui = (const float*)d_in[6];
  const float* uo = (const float*)d_in[7];
  const float* uc = (const float*)d_in[8];
  const float* bf = (const float*)d_in[9];
  const float* bi = (const float*)d_in[10];
  const float* bo = (const float*)d_in[11];
  const float* bc = (const float*)d_in[12];
  float* out = (float*)d_out;

  dim3 block(256);
  dim3 grid(BATCH / BPB);   // 2048 blocks
  hipLaunchKernelGGL(lstm_mfma, grid, block, 0, stream,
                     x, wf, wi, wo, wc, uf, ui, uo, uc, bf, bi, bo, bc, out);
}

// Round 7
// 47.416 us; speedup vs baseline: 4.1758x; 1.2776x over previous
//
#include <hip/hip_runtime.h>
#include <hip/hip_bf16.h>

namespace {

constexpr int T = 5, F = 30, H = 20;
constexpr int BATCH = 131072;
constexpr int BPB = 64;    // batch rows per block (16 per wave)
constexpr int XS = 36;     // x LDS row stride (dwords): 16B-aligned b128, 2-way banks
constexpr int HS = 36;     // h LDS row stride
constexpr int TH = T * H;  // 100

typedef __attribute__((ext_vector_type(8))) short bf16x8;
typedef __attribute__((ext_vector_type(4))) float f32x4;

union FragU { __hip_bfloat162 h2[4]; unsigned u32[4]; bf16x8 v; };

__device__ __forceinline__ float sig(float v) {
  return __builtin_amdgcn_rcpf(1.0f + __builtin_amdgcn_exp2f(v * -1.44269504f));
}
// tanh(v) = 2*sigmoid(2v) - 1; saturates correctly at +-inf, no NaN paths.
__device__ __forceinline__ float tanh_s(float v) {
  return fmaf(2.0f,
              __builtin_amdgcn_rcpf(1.0f + __builtin_amdgcn_exp2f(v * -2.88539008f)),
              -1.0f);
}

// Barrier-free: each wave owns 16 batch rows end-to-end. All LDS regions are
// wave-private (rows 16*wv..16*wv+15); ordering within a wave is enforced by
// compiler-inserted lgkmcnt waits. No __syncthreads anywhere.
__global__ __launch_bounds__(256, 3) void lstm_wave(
    const float* __restrict__ x,
    const float* __restrict__ wf, const float* __restrict__ wi,
    const float* __restrict__ wo, const float* __restrict__ wc,
    const float* __restrict__ uf, const float* __restrict__ ui,
    const float* __restrict__ uo, const float* __restrict__ uc,
    const float* __restrict__ bf, const float* __restrict__ bi,
    const float* __restrict__ bo, const float* __restrict__ bc,
    float* __restrict__ out)
{
  const int tid  = threadIdx.x;
  const int lane = tid & 63;
  const int wv   = tid >> 6;          // wave id: owns rows 16wv..16wv+15
  const int r15  = lane & 15;
  const int q    = lane >> 4;         // k-slice 8q..8q+7 / hidden sub-index
  const int b0   = blockIdx.x * BPB;
  const int w0   = 16 * wv;           // wave's first block-local row

  // Wave's x slab is CONTIGUOUS: rows (b0+w0)..(b0+w0+15) = 9600B.
  const float* xwave = x + (size_t)(b0 + w0) * (T * F);
  float*       owave = out + (size_t)(b0 + w0) * (T * H);

  __shared__ __align__(16) float xs[2][BPB][XS];   // 18.4 KB, wave-private rows
  __shared__ __align__(16) float hb[BPB][HS];      //  9.2 KB
  __shared__ __align__(16) float hist[BPB][TH];    // 25.6 KB

  // ---- A-side fragments. W rows hidx = 4*jj + gate; bias folded at k==30
  // (x's virtual col 30 == 1.0). k0 = 8q+2e is always even -> only k0 can be 30.
  const int gA = r15 & 3;
  const int jA = r15 >> 2;
  const float* Wg = (gA == 0) ? wf : (gA == 1) ? wi : (gA == 2) ? wo : wc;
  const float* Ug = (gA == 0) ? uf : (gA == 1) ? ui : (gA == 2) ? uo : uc;
  const float* Bg = (gA == 0) ? bf : (gA == 1) ? bi : (gA == 2) ? bo : bc;

  bf16x8 wfrag[5], ufrag[5];
#pragma unroll
  for (int m = 0; m < 5; ++m) {
    const int jj = 4 * m + jA;
    FragU fw, fu;
#pragma unroll
    for (int e = 0; e < 4; ++e) {
      const int k0 = 8 * q + 2 * e, k1 = k0 + 1;
      float w0v = (k0 < F) ? Wg[k0 * H + jj] : (k0 == F ? Bg[jj] : 0.f);
      float w1v = (k1 < F) ? Wg[k1 * H + jj] : 0.f;
      fw.h2[e] = __float22bfloat162_rn(float2{w0v, w1v});
      float u0 = (k0 < H) ? Ug[k0 * H + jj] : 0.f;
      float u1 = (k1 < H) ? Ug[k1 * H + jj] : 0.f;
      fu.h2[e] = __float22bfloat162_rn(float2{u0, u1});
    }
    wfrag[m] = fw.v;
    ufrag[m] = fu.v;
  }

  // ---- zero hb pad cols 20..31 for this wave's rows (16*12 = 192 = 64*3) ----
#pragma unroll
  for (int k = 0; k < 3; ++k) {
    int i = lane + 64 * k;
    hb[w0 + i / 12][20 + i % 12] = 0.f;
  }

  // ---- stage x(t=0): 240 float2, contiguous slab, wave-coalesced ----
#pragma unroll
  for (int k = 0; k < 4; ++k) {
    int f2 = lane + 64 * k;
    if (f2 < 240) {
      int r = f2 / 15, c = 2 * (f2 % 15);
      float2 v = *(const float2*)(xwave + r * (T * F) + c);
      *(float2*)&xs[0][w0 + r][c] = v;
    }
  }

  float cst[5];
#pragma unroll
  for (int m = 0; m < 5; ++m) cst[m] = 0.f;

  float2 pf2[4];
  int cur = 0;
  for (int t = 0; t < T; ++t) {
    // B-frag of x^T from wave-private LDS; q==3's e=3 slot = {1.0,0} (bias col)
    FragU fx;
    {
      const float* xp = &xs[cur][w0 + r15][8 * q];
      float4 lo = *(const float4*)(xp);
      float4 hi = *(const float4*)(xp + 4);
      fx.h2[0] = __float22bfloat162_rn(float2{lo.x, lo.y});
      fx.h2[1] = __float22bfloat162_rn(float2{lo.z, lo.w});
      fx.h2[2] = __float22bfloat162_rn(float2{hi.x, hi.y});
      fx.h2[3] = __float22bfloat162_rn(float2{hi.z, hi.w});
      if (q == 3) fx.u32[3] = 0x00003F80u;   // bf16x2 {1.0, 0.0}
    }

    // T14: issue next-t global loads now; LDS write lands after compute
    if (t + 1 < T) {
#pragma unroll
      for (int k = 0; k < 4; ++k) {
        int f2 = lane + 64 * k;
        if (f2 < 240) {
          int r = f2 / 15, c = 2 * (f2 % 15);
          pf2[k] = *(const float2*)(xwave + r * (T * F) + (t + 1) * F + c);
        }
      }
    }

    f32x4 acc[5];
#pragma unroll
    for (int m = 0; m < 5; ++m)
      acc[m] = __builtin_amdgcn_mfma_f32_16x16x32_bf16(
          wfrag[m], fx.v, f32x4{0.f, 0.f, 0.f, 0.f}, 0, 0, 0);

    if (t > 0) {   // recurrent term (t=0: h==0, matches reference)
      FragU fh;
      const float* hp = &hb[w0 + r15][8 * q];
      float4 lo = *(const float4*)(hp);
      float4 hi = *(const float4*)(hp + 4);
      fh.h2[0] = __float22bfloat162_rn(float2{lo.x, lo.y});
      fh.h2[1] = __float22bfloat162_rn(float2{lo.z, lo.w});
      fh.h2[2] = __float22bfloat162_rn(float2{hi.x, hi.y});
      fh.h2[3] = __float22bfloat162_rn(float2{hi.z, hi.w});
#pragma unroll
      for (int m = 0; m < 5; ++m)
        acc[m] = __builtin_amdgcn_mfma_f32_16x16x32_bf16(
            ufrag[m], fh.v, acc[m], 0, 0, 0);
    }

    // gate math: lane-local (acc[m] = f,i,o,c of hidden jj=4m+q, own row)
#pragma unroll
    for (int m = 0; m < 5; ++m) {
      float fg = sig(acc[m][0]);
      float ig = sig(acc[m][1]);
      float og = sig(acc[m][2]);
      float ch = tanh_s(acc[m][3]);
      float cn = fmaf(fg, cst[m], ig * ch);
      cst[m] = cn;
      float hn = og * tanh_s(cn);
      const int jj = 4 * m + q;
      hb[w0 + r15][jj] = hn;             // for next-t recurrent frag
      hist[w0 + r15][t * H + jj] = hn;   // for final coalesced drain
    }

    // write staged x(t+1) into the other buffer (wave-private, no hazard)
    if (t + 1 < T) {
#pragma unroll
      for (int k = 0; k < 4; ++k) {
        int f2 = lane + 64 * k;
        if (f2 < 240) {
          int r = f2 / 15, c = 2 * (f2 % 15);
          *(float2*)&xs[cur ^ 1][w0 + r][c] = pf2[k];
        }
      }
    }
    cur ^= 1;
  }

  // ---- drain: wave's contiguous 6.4 KB out slab, full-line float4 stores ----
#pragma unroll
  for (int k = 0; k < 7; ++k) {
    int f4 = lane + 64 * k;
    if (f4 < 16 * TH / 4) {
      int r = f4 / 25, c4 = 4 * (f4 % 25);
      float4 v = *(const float4*)&hist[w0 + r][c4];
      *(float4*)(owave + r * TH + c4) = v;
    }
  }
}

} // namespace

extern "C" void kernel_launch(void* const* d_in, const int* in_sizes, int n_in,
                              void* d_out, int out_size, void* d_ws, size_t ws_size,
                              hipStream_t stream) {
  const float* x  = (const float*)d_in[0];
  const float* wf = (const float*)d_in[1];
  const float* wi = (const float*)d_in[2];
  const float* wo = (const float*)d_in[3];
  const float* wc = (const float*)d_in[4];
  const float* uf = (const float*)d_in[5];
  const float* ui = (const float*)d_in[6];
  const float* uo = (const float*)d_in[7];
  const float* uc = (const float*)d_in[8];
  const float* bf = (const float*)d_in[9];
  const float* bi = (const float*)d_in[10];
  const float* bo = (const float*)d_in[11];
  const float* bc = (const float*)d_in[12];
  float* out = (float*)d_out;

  dim3 block(256);
  dim3 grid(BATCH / BPB);   // 2048 blocks
  hipLaunchKernelGGL(lstm_wave, grid, block, 0, stream,
                     x, wf, wi, wo, wc, uf, ui, uo, uc, bf, bi, bo, bc, out);
}